// Round 1
// baseline (197.802 us; speedup 1.0000x reference)
//
#include <hip/hip_runtime.h>
#include <cstdint>
#include <cstddef>

#define NUM_CLASSES 80
#define NCLS1 81
#define NCAND 200
#define MAX_SEGS 50
#define FH 128
#define FW 128
#define NMS_THR 0.65f
#define CLS_OFFSET 129.0f
#define OH 512
#define OW 512

typedef unsigned int u32;
typedef unsigned long long u64;

__device__ __forceinline__ u32 ord_of_float(float f) {
  u32 u = __float_as_uint(f);
  return (u & 0x80000000u) ? ~u : (u | 0x80000000u);
}
__device__ __forceinline__ float float_of_ord(u32 o) {
  u32 u = (o & 0x80000000u) ? (o ^ 0x80000000u) : ~o;
  return __uint_as_float(u);
}

// ---------------- K1: per-feature mask validity + bounding box ----------------
__global__ void box_kernel(const float* __restrict__ seg,
                           float* __restrict__ boxes, int* __restrict__ validF) {
  int f = blockIdx.x;
  int t = threadIdx.x;  // 0..127, one row each
  __shared__ int rowAny[FH];
  __shared__ u32 colBits[4];
  if (t < 4) colBits[t] = 0;
  __syncthreads();

  const float* row = seg + (size_t)f * (FH * FW) + (size_t)t * FW;
  u32 local[4] = {0, 0, 0, 0};
  int any = 0;
  for (int i = 0; i < FW; ++i) {
    if (row[i] > 0.0f) { any = 1; local[i >> 5] |= (1u << (i & 31)); }
  }
  rowAny[t] = any;
  for (int w = 0; w < 4; ++w)
    if (local[w]) atomicOr(&colBits[w], local[w]);
  __syncthreads();

  if (t == 0) {
    int firstR = -1, lastR = -1;
    for (int r = 0; r < FH; ++r)
      if (rowAny[r]) { if (firstR < 0) firstR = r; lastR = r; }
    int firstC = -1, lastC = -1;
    for (int w = 0; w < 4; ++w) {
      u32 b = colBits[w];
      if (b) {
        if (firstC < 0) firstC = w * 32 + (__ffs(b) - 1);
        lastC = w * 32 + (31 - __clz((int)b));
      }
    }
    float x1, y1, x2, y2; int valid;
    if (firstR < 0) {
      // empty mask: argmax of all-False = 0 -> box [0,0,W,H] (ref semantics)
      valid = 0; x1 = 0.0f; y1 = 0.0f; x2 = (float)FW; y2 = (float)FH;
    } else {
      valid = 1;
      y1 = (float)firstR; y2 = (float)(lastR + 1);
      x1 = (float)firstC; x2 = (float)(lastC + 1);
    }
    boxes[f * 4 + 0] = x1; boxes[f * 4 + 1] = y1;
    boxes[f * 4 + 2] = x2; boxes[f * 4 + 3] = y2;
    validF[f] = valid;
  }
}

// ---------------- K2: per-image exact top-200 -> NMS -> top-50 ----------------
__global__ void __launch_bounds__(256)
select_nms_kernel(const float* __restrict__ cls, const float* __restrict__ boxes,
                  const int* __restrict__ validF, int F,
                  float* __restrict__ out,
                  int* __restrict__ finFeatWs, int* __restrict__ finValidWs,
                  size_t scoresOff, size_t validOff) {
  const int img = blockIdx.x;
  const int tid = threadIdx.x;
  const int NS = F * NUM_CLASSES;  // 8000

  __shared__ u32 ords[8000];
  __shared__ u32 hist[256];
  __shared__ u64 gkeys[1024];
  __shared__ int cnt;
  __shared__ u64 prefix;
  __shared__ int R;
  __shared__ float candScore[NCAND];
  __shared__ int candFeat[NCAND], candLabel[NCAND];
  __shared__ float candBox[NCAND][4];
  __shared__ u64 supp[NCAND][4];
  __shared__ int finFeat[MAX_SEGS], finLabel[MAX_SEGS], finValid[MAX_SEGS];
  __shared__ float finScore[MAX_SEGS];

  // (a) scores -> orderable keys
  for (int idx = tid; idx < NS; idx += blockDim.x) {
    int f = idx / NUM_CLASSES, c = idx - f * NUM_CLASSES;
    int g = img * F + f;
    float logit = cls[(size_t)g * NCLS1 + c];
    float s = validF[g] ? (1.0f / (1.0f + expf(-logit))) : -1.0f;
    ords[idx] = ord_of_float(s);
  }
  if (tid == 0) { prefix = 0; R = NCAND; cnt = 0; }
  __syncthreads();

  // (b) 4 radix passes: find exact 200th-largest score value s*
  for (int p = 0; p < 4; ++p) {
    for (int i = tid; i < 256; i += blockDim.x) hist[i] = 0;
    __syncthreads();
    int shift = 24 - 8 * p;
    u64 pfx = prefix;
    for (int idx = tid; idx < NS; idx += blockDim.x) {
      u64 o = (u64)ords[idx];
      if ((o >> (shift + 8)) == pfx) atomicAdd(&hist[(o >> shift) & 0xFF], 1u);
    }
    __syncthreads();
    if (tid == 0) {
      int cum = 0, Rl = R;
      for (int v = 255; v >= 0; --v) {
        int c = (int)hist[v];
        if (cum + c >= Rl) { prefix = (prefix << 8) | (u64)v; R = Rl - cum; break; }
        cum += c;
      }
    }
    __syncthreads();
  }
  u32 sStar = (u32)prefix;

  // (c) gather all keys with ord >= s*  (count >= 200 by construction)
  for (int i = tid; i < 1024; i += blockDim.x) gkeys[i] = 0;
  __syncthreads();
  for (int idx = tid; idx < NS; idx += blockDim.x) {
    u32 o = ords[idx];
    if (o >= sStar) {
      int pos = atomicAdd(&cnt, 1);
      if (pos < 1024) gkeys[pos] = ((u64)o << 13) | (u64)(8191 - idx);
    }
  }
  __syncthreads();

  // (d) bitonic sort 1024 keys, descending (desc score, then ascending idx)
  for (int k = 2; k <= 1024; k <<= 1) {
    for (int j = k >> 1; j > 0; j >>= 1) {
      for (int t = tid; t < 1024; t += blockDim.x) {
        int ixj = t ^ j;
        if (ixj > t) {
          u64 a = gkeys[t], b = gkeys[ixj];
          bool desc = ((t & k) == 0);
          if (desc ? (a < b) : (a > b)) { gkeys[t] = b; gkeys[ixj] = a; }
        }
      }
      __syncthreads();
    }
  }

  // (e) decode top-200 candidates
  for (int t = tid; t < NCAND; t += blockDim.x) {
    u64 key = gkeys[t];
    int idx = 8191 - (int)(key & 0x1FFF);
    u32 o = (u32)(key >> 13);
    float s = float_of_ord(o);
    int f = idx / NUM_CLASSES, c = idx - f * NUM_CLASSES;
    candScore[t] = s; candFeat[t] = f; candLabel[t] = c;
    float off = (float)c * CLS_OFFSET;
    int g = img * F + f;
    candBox[t][0] = boxes[g * 4 + 0] + off;
    candBox[t][1] = boxes[g * 4 + 1] + off;
    candBox[t][2] = boxes[g * 4 + 2] + off;
    candBox[t][3] = boxes[g * 4 + 3] + off;
    supp[t][0] = 0; supp[t][1] = 0; supp[t][2] = 0; supp[t][3] = 0;
  }
  __syncthreads();

  // (f) pairwise IoU -> suppression bitmasks (j < i)
  for (int pIdx = tid; pIdx < NCAND * NCAND; pIdx += blockDim.x) {
    int i = pIdx / NCAND, j = pIdx - i * NCAND;
    if (j < i) {
      float ax1 = candBox[i][0], ay1 = candBox[i][1], ax2 = candBox[i][2], ay2 = candBox[i][3];
      float bx1 = candBox[j][0], by1 = candBox[j][1], bx2 = candBox[j][2], by2 = candBox[j][3];
      float areaA = (ax2 - ax1) * (ay2 - ay1);
      float areaB = (bx2 - bx1) * (by2 - by1);
      float lx = fmaxf(ax1, bx1), ly = fmaxf(ay1, by1);
      float rx = fminf(ax2, bx2), ry = fminf(ay2, by2);
      float w = fmaxf(rx - lx, 0.0f), h = fmaxf(ry - ly, 0.0f);
      float inter = w * h;
      float iou = inter / ((areaA + areaB - inter) + 1e-9f);
      if (iou > NMS_THR) atomicOr(&supp[i][j >> 6], 1ull << (j & 63));
    }
  }
  __syncthreads();

  // (g) serial greedy NMS + final top-50 (kept in order, then non-kept ascending)
  if (tid == 0) {
    u64 keepW[4] = {0, 0, 0, 0};
    int nf = 0;
    for (int i = 0; i < NCAND; ++i) {
      bool valid_i = candScore[i] > -0.5f;
      bool sup = ((supp[i][0] & keepW[0]) | (supp[i][1] & keepW[1]) |
                  (supp[i][2] & keepW[2]) | (supp[i][3] & keepW[3])) != 0ull;
      bool k = valid_i && !sup;
      if (k) {
        keepW[i >> 6] |= (1ull << (i & 63));
        if (nf < MAX_SEGS) {
          finFeat[nf] = candFeat[i]; finLabel[nf] = candLabel[i];
          finScore[nf] = candScore[i]; finValid[nf] = 1; ++nf;
        }
      }
    }
    for (int i = 0; i < NCAND && nf < MAX_SEGS; ++i) {
      if (!((keepW[i >> 6] >> (i & 63)) & 1ull)) {
        finFeat[nf] = candFeat[i]; finLabel[nf] = candLabel[i];
        finScore[nf] = candScore[i]; finValid[nf] = 0; ++nf;
      }
    }
  }
  __syncthreads();

  // (h) write labels/scores/valid outputs + ws for interp
  if (tid < MAX_SEGS) {
    int o = img * MAX_SEGS + tid;
    out[o] = (float)finLabel[tid];
    out[scoresOff + (size_t)o] = finValid[tid] ? finScore[tid] : 0.0f;
    out[validOff + (size_t)o] = finValid[tid] ? 1.0f : 0.0f;
    finFeatWs[o] = finFeat[tid];
    finValidWs[o] = finValid[tid];
  }
}

// ---------------- K3: bilinear 128->512 upsample + threshold ----------------
__global__ void __launch_bounds__(256)
interp_kernel(const float* __restrict__ seg, const int* __restrict__ finFeat,
              const int* __restrict__ finValid, float* __restrict__ outMasks, int F) {
  int bm = blockIdx.x;   // img*MAX_SEGS + m
  int y  = blockIdx.y;   // output row
  int tid = threadIdx.x;
  float* orow = outMasks + (size_t)bm * (OH * OW) + (size_t)y * OW;

  if (!finValid[bm]) {
    float2 z; z.x = 0.0f; z.y = 0.0f;
    reinterpret_cast<float2*>(orow)[tid] = z;
    return;
  }
  int img = bm / MAX_SEGS;
  int f = finFeat[bm];
  const float* src = seg + ((size_t)(img * F + f)) * (FH * FW);

  // half-pixel-center bilinear, scale 4: src = (y+0.5)/4 - 0.5
  int yq = y >> 2, ry = y & 3;
  int y0 = (ry < 2) ? yq - 1 : yq;
  double wy0, wy1;
  switch (ry) {
    case 0: wy0 = 0.375; wy1 = 0.625; break;
    case 1: wy0 = 0.125; wy1 = 0.875; break;
    case 2: wy0 = 0.875; wy1 = 0.125; break;
    default: wy0 = 0.625; wy1 = 0.375; break;
  }
  int y1 = y0 + 1;
  if (y0 < 0)      { y0 = 0;      wy0 = 0.0; wy1 = 1.0; }  // edge renorm == single tap
  if (y1 > FH - 1) { y1 = FH - 1; wy1 = 0.0; wy0 = 1.0; }
  const float* r0p = src + (size_t)y0 * FW;
  const float* r1p = src + (size_t)y1 * FW;

  float vals[2];
#pragma unroll
  for (int e = 0; e < 2; ++e) {
    int x = tid * 2 + e;
    int xq = x >> 2, rx = x & 3;
    int x0 = (rx < 2) ? xq - 1 : xq;
    double wx0, wx1;
    switch (rx) {
      case 0: wx0 = 0.375; wx1 = 0.625; break;
      case 1: wx0 = 0.125; wx1 = 0.875; break;
      case 2: wx0 = 0.875; wx1 = 0.125; break;
      default: wx0 = 0.625; wx1 = 0.375; break;
    }
    int x1 = x0 + 1;
    if (x0 < 0)      { x0 = 0;      wx0 = 0.0; wx1 = 1.0; }
    if (x1 > FW - 1) { x1 = FW - 1; wx1 = 0.0; wx0 = 1.0; }
    double v00 = (double)r0p[x0], v01 = (double)r0p[x1];
    double v10 = (double)r1p[x0], v11 = (double)r1p[x1];
    double hv0 = wy0 * v00 + wy1 * v10;
    double hv1 = wy0 * v01 + wy1 * v11;
    double val = wx0 * hv0 + wx1 * hv1;
    vals[e] = (val > 0.0) ? 1.0f : 0.0f;
  }
  float2 res; res.x = vals[0]; res.y = vals[1];
  reinterpret_cast<float2*>(orow)[tid] = res;
}

// ---------------- host launch ----------------
extern "C" void kernel_launch(void* const* d_in, const int* in_sizes, int n_in,
                              void* d_out, int out_size, void* d_ws, size_t ws_size,
                              hipStream_t stream) {
  const float* cls = (const float*)d_in[0];
  const float* seg = (const float*)d_in[1];
  const int B = 2;  // fixed by setup_inputs
  int totalF = in_sizes[0] / NCLS1;      // 200
  int F = totalF / B;                    // 100

  float* out = (float*)d_out;
  // workspace layout
  float* boxes   = (float*)d_ws;                       // totalF*4 floats
  int*   validF  = (int*)(boxes + (size_t)totalF * 4); // totalF ints
  int*   finFeat = validF + totalF;                    // B*MAX_SEGS ints
  int*   finValid = finFeat + B * MAX_SEGS;            // B*MAX_SEGS ints

  const size_t labelsN   = (size_t)B * MAX_SEGS;             // 100
  const size_t maskElems = (size_t)B * MAX_SEGS * OH * OW;   // 26,214,400
  const size_t scoresOff = labelsN + maskElems;
  const size_t validOff  = scoresOff + labelsN;

  box_kernel<<<totalF, FH, 0, stream>>>(seg, boxes, validF);
  select_nms_kernel<<<B, 256, 0, stream>>>(cls, boxes, validF, F, out,
                                           finFeat, finValid, scoresOff, validOff);
  interp_kernel<<<dim3(B * MAX_SEGS, OH), 256, 0, stream>>>(seg, finFeat, finValid,
                                                            out + labelsN, F);
}

// Round 2
// 136.037 us; speedup vs baseline: 1.4540x; 1.4540x over previous
//
#include <hip/hip_runtime.h>
#include <cstdint>
#include <cstddef>

#define NUM_CLASSES 80
#define NCLS1 81
#define NCAND 200
#define MAX_SEGS 50
#define FH 128
#define FW 128
#define NMS_THR 0.65f
#define CLS_OFFSET 129.0f
#define OH 512
#define OW 512

typedef unsigned int u32;
typedef unsigned long long u64;

__device__ __forceinline__ u32 ord_of_float(float f) {
  u32 u = __float_as_uint(f);
  return (u & 0x80000000u) ? ~u : (u | 0x80000000u);
}
__device__ __forceinline__ float float_of_ord(u32 o) {
  u32 u = (o & 0x80000000u) ? (o ^ 0x80000000u) : ~o;
  return __uint_as_float(u);
}

// ---------------- K1: per-feature mask validity + bounding box ----------------
// thread t = column t; coalesced loads (wave reads 256B contiguous per row).
__global__ void __launch_bounds__(FH)
box_kernel(const float* __restrict__ seg,
           float* __restrict__ boxes, int* __restrict__ validF) {
  int f = blockIdx.x;
  int t = threadIdx.x;  // 0..127 column
  __shared__ u32 rowBits[4];
  __shared__ u32 colBits[4];
  if (t < 4) rowBits[t] = 0;
  __syncthreads();

  const float* base = seg + (size_t)f * (FH * FW);
  bool colAny = false;
  u32 myRow[4] = {0, 0, 0, 0};
  int lane = t & 63;
  for (int r = 0; r < FH; ++r) {
    bool p = base[(size_t)r * FW + t] > 0.0f;
    colAny |= p;
    u64 b = __ballot(p);
    if (lane == 0) myRow[r >> 5] |= (u32)(b != 0ull) << (r & 31);
  }
  u64 cb = __ballot(colAny);
  if (lane == 0) {
    int w = (t >> 6) * 2;  // wave 0 -> words 0,1 ; wave 1 -> words 2,3
    colBits[w] = (u32)cb;
    colBits[w + 1] = (u32)(cb >> 32);
    for (int i = 0; i < 4; ++i)
      if (myRow[i]) atomicOr(&rowBits[i], myRow[i]);
  }
  __syncthreads();

  if (t == 0) {
    int firstR = -1, lastR = -1;
    for (int w = 0; w < 4; ++w) {
      u32 b = rowBits[w];
      if (b) { if (firstR < 0) firstR = w * 32 + (__ffs(b) - 1); lastR = w * 32 + 31 - __clz((int)b); }
    }
    int firstC = -1, lastC = -1;
    for (int w = 0; w < 4; ++w) {
      u32 b = colBits[w];
      if (b) { if (firstC < 0) firstC = w * 32 + (__ffs(b) - 1); lastC = w * 32 + 31 - __clz((int)b); }
    }
    float x1, y1, x2, y2; int valid;
    if (firstR < 0) {
      valid = 0; x1 = 0.0f; y1 = 0.0f; x2 = (float)FW; y2 = (float)FH;
    } else {
      valid = 1;
      y1 = (float)firstR; y2 = (float)(lastR + 1);
      x1 = (float)firstC; x2 = (float)(lastC + 1);
    }
    boxes[f * 4 + 0] = x1; boxes[f * 4 + 1] = y1;
    boxes[f * 4 + 2] = x2; boxes[f * 4 + 3] = y2;
    validF[f] = valid;
  }
}

// ---------------- K2: per-image exact top-200 -> NMS -> top-50 ----------------
__global__ void __launch_bounds__(1024)
select_nms_kernel(const float* __restrict__ cls, const float* __restrict__ boxes,
                  const int* __restrict__ validF, int F,
                  float* __restrict__ out,
                  int* __restrict__ finFeatWs, int* __restrict__ finValidWs,
                  size_t scoresOff, size_t validOff) {
  const int img = blockIdx.x;
  const int tid = threadIdx.x;
  const int NS = F * NUM_CLASSES;  // 8000

  __shared__ u32 ords[8000];
  __shared__ u32 hist[256];
  __shared__ u64 keyS[NCAND];      // strict-greater keys
  __shared__ u32 eqIdx[1024];      // indices of ties at s*
  __shared__ int cntS, cntE;
  __shared__ u64 selPrefix;
  __shared__ int selR;
  __shared__ float candScore[NCAND];
  __shared__ int candFeat[NCAND], candLabel[NCAND];
  __shared__ float candBox[NCAND][4];
  __shared__ u64 supp[NCAND][4];
  __shared__ int keepFlag[NCAND];
  __shared__ int finFeat[MAX_SEGS], finLabel[MAX_SEGS], finValid[MAX_SEGS];
  __shared__ float finScore[MAX_SEGS];

  // (a) scores -> orderable keys
  for (int idx = tid; idx < NS; idx += blockDim.x) {
    int f = idx / NUM_CLASSES, c = idx - f * NUM_CLASSES;
    int g = img * F + f;
    float logit = cls[(size_t)g * NCLS1 + c];
    float s = validF[g] ? (1.0f / (1.0f + expf(-logit))) : -1.0f;
    ords[idx] = ord_of_float(s);
  }
  if (tid == 0) { selPrefix = 0; selR = NCAND; cntS = 0; cntE = 0; }
  __syncthreads();

  // (b) 4 radix passes with wave-parallel suffix-scan selection
  for (int p = 0; p < 4; ++p) {
    for (int i = tid; i < 256; i += blockDim.x) hist[i] = 0;
    __syncthreads();
    int shift = 24 - 8 * p;
    u64 pfx = selPrefix;
    for (int idx = tid; idx < NS; idx += blockDim.x) {
      u64 o = (u64)ords[idx];
      if ((o >> (shift + 8)) == pfx) atomicAdd(&hist[(o >> shift) & 0xFF], 1u);
    }
    __syncthreads();
    if (tid < 64) {
      int l = tid;
      u32 h0 = hist[4 * l + 0], h1 = hist[4 * l + 1];
      u32 h2 = hist[4 * l + 2], h3 = hist[4 * l + 3];
      u32 sl = h0 + h1 + h2 + h3;
      u32 suf = sl;
#pragma unroll
      for (int d = 1; d < 64; d <<= 1) {
        u32 o = __shfl_down(suf, d);
        if (l + d < 64) suf += o;
      }
      u32 above = suf - sl;           // sum of bins >= 4(l+1)
      u32 S3 = above + h3;
      u32 S2 = S3 + h2;
      u32 S1 = S2 + h1;
      u32 S0 = S1 + h0;
      u32 R = (u32)selR;
      u64 base = pfx << 8;
      if (S0 >= R && S1 < R)      { selPrefix = base | (u64)(4 * l + 0); selR = (int)(R - S1); }
      else if (S1 >= R && S2 < R) { selPrefix = base | (u64)(4 * l + 1); selR = (int)(R - S2); }
      else if (S2 >= R && S3 < R) { selPrefix = base | (u64)(4 * l + 2); selR = (int)(R - S3); }
      else if (S3 >= R && above < R) { selPrefix = base | (u64)(4 * l + 3); selR = (int)(R - above); }
    }
    __syncthreads();
  }
  u32 sStar = (u32)selPrefix;
  int Rfin = selR;  // how many ties at s* belong in the top-200 (>=1)

  // (c) gather strict-greater keys (count = 200 - Rfin <= 199) and tie indices
  for (int idx = tid; idx < NS; idx += blockDim.x) {
    u32 o = ords[idx];
    if (o > sStar) {
      int pos = atomicAdd(&cntS, 1);
      keyS[pos] = ((u64)o << 13) | (u64)(8191 - idx);
    } else if (o == sStar) {
      int pos = atomicAdd(&cntE, 1);
      if (pos < 1024) eqIdx[pos] = idx;
    }
  }
  __syncthreads();
  int nS = cntS;
  int nE = cntE < 1024 ? cntE : 1024;

  // (d) rank-and-scatter: strict by key desc; ties by index asc (stable top_k)
  for (int t = tid; t < nS; t += blockDim.x) {
    u64 k = keyS[t];
    int r = 0;
    for (int s = 0; s < nS; ++s) r += (keyS[s] > k) ? 1 : 0;
    u32 o = (u32)(k >> 13);
    int idx = 8191 - (int)(k & 0x1FFF);
    int f = idx / NUM_CLASSES, c = idx - f * NUM_CLASSES;
    float sc = float_of_ord(o);
    float off = (float)c * CLS_OFFSET;
    int g = img * F + f;
    candScore[r] = sc; candFeat[r] = f; candLabel[r] = c;
    candBox[r][0] = boxes[g * 4 + 0] + off;
    candBox[r][1] = boxes[g * 4 + 1] + off;
    candBox[r][2] = boxes[g * 4 + 2] + off;
    candBox[r][3] = boxes[g * 4 + 3] + off;
  }
  for (int t = tid; t < nE; t += blockDim.x) {
    u32 myidx = eqIdx[t];
    int r = 0;
    for (int s = 0; s < nE; ++s) r += (eqIdx[s] < myidx) ? 1 : 0;
    if (r < Rfin) {
      int slot = nS + r;
      int idx = (int)myidx;
      int f = idx / NUM_CLASSES, c = idx - f * NUM_CLASSES;
      float sc = float_of_ord(sStar);
      float off = (float)c * CLS_OFFSET;
      int g = img * F + f;
      candScore[slot] = sc; candFeat[slot] = f; candLabel[slot] = c;
      candBox[slot][0] = boxes[g * 4 + 0] + off;
      candBox[slot][1] = boxes[g * 4 + 1] + off;
      candBox[slot][2] = boxes[g * 4 + 2] + off;
      candBox[slot][3] = boxes[g * 4 + 3] + off;
    }
  }
  for (int t = tid; t < NCAND * 4; t += blockDim.x)
    supp[t >> 2][t & 3] = 0;
  __syncthreads();

  // (e) pairwise IoU -> suppression bitmasks (j < i)
  for (int pIdx = tid; pIdx < NCAND * NCAND; pIdx += blockDim.x) {
    int i = pIdx / NCAND, j = pIdx - i * NCAND;
    if (j < i) {
      float ax1 = candBox[i][0], ay1 = candBox[i][1], ax2 = candBox[i][2], ay2 = candBox[i][3];
      float bx1 = candBox[j][0], by1 = candBox[j][1], bx2 = candBox[j][2], by2 = candBox[j][3];
      float areaA = (ax2 - ax1) * (ay2 - ay1);
      float areaB = (bx2 - bx1) * (by2 - by1);
      float lx = fmaxf(ax1, bx1), ly = fmaxf(ay1, by1);
      float rx = fminf(ax2, bx2), ry = fminf(ay2, by2);
      float w = fmaxf(rx - lx, 0.0f), h = fmaxf(ry - ly, 0.0f);
      float inter = w * h;
      float iou = inter / ((areaA + areaB - inter) + 1e-9f);
      if (iou > NMS_THR) atomicOr(&supp[i][j >> 6], 1ull << (j & 63));
    }
  }
  __syncthreads();

  // (f) serial greedy NMS, software-pipelined (prefetch row i+1)
  if (tid == 0) {
    u64 k0 = 0, k1 = 0, k2 = 0, k3 = 0;
    int nf = 0;
    u64 n0 = supp[0][0], n1 = supp[0][1], n2 = supp[0][2], n3 = supp[0][3];
    float nsc = candScore[0];
    for (int i = 0; i < NCAND; ++i) {
      u64 r0 = n0, r1 = n1, r2 = n2, r3 = n3;
      float sc = nsc;
      if (i + 1 < NCAND) {
        n0 = supp[i + 1][0]; n1 = supp[i + 1][1];
        n2 = supp[i + 1][2]; n3 = supp[i + 1][3];
        nsc = candScore[i + 1];
      }
      bool valid_i = sc > -0.5f;
      bool sup = ((r0 & k0) | (r1 & k1) | (r2 & k2) | (r3 & k3)) != 0ull;
      if (valid_i && !sup) {
        u64 bit = 1ull << (i & 63);
        if (i < 64) k0 |= bit; else if (i < 128) k1 |= bit;
        else if (i < 192) k2 |= bit; else k3 |= bit;
        keepFlag[i] = 1;
        if (nf < MAX_SEGS) {
          finFeat[nf] = candFeat[i]; finLabel[nf] = candLabel[i];
          finScore[nf] = sc; finValid[nf] = 1; ++nf;
        }
      } else {
        keepFlag[i] = 0;
      }
    }
    for (int i = 0; i < NCAND && nf < MAX_SEGS; ++i) {
      if (!keepFlag[i]) {
        finFeat[nf] = candFeat[i]; finLabel[nf] = candLabel[i];
        finScore[nf] = candScore[i]; finValid[nf] = 0; ++nf;
      }
    }
  }
  __syncthreads();

  // (g) write labels/scores/valid outputs + ws for interp
  if (tid < MAX_SEGS) {
    int o = img * MAX_SEGS + tid;
    out[o] = (float)finLabel[tid];
    out[scoresOff + (size_t)o] = finValid[tid] ? finScore[tid] : 0.0f;
    out[validOff + (size_t)o] = finValid[tid] ? 1.0f : 0.0f;
    finFeatWs[o] = finFeat[tid];
    finValidWs[o] = finValid[tid];
  }
}

// ---------------- K3: bilinear 128->512 upsample + threshold ----------------
__global__ void __launch_bounds__(256)
interp_kernel(const float* __restrict__ seg, const int* __restrict__ finFeat,
              const int* __restrict__ finValid, float* __restrict__ outMasks, int F) {
  int bm = blockIdx.x;   // img*MAX_SEGS + m
  int y  = blockIdx.y;   // output row
  int tid = threadIdx.x;
  float* orow = outMasks + (size_t)bm * (OH * OW) + (size_t)y * OW;

  if (!finValid[bm]) {
    float2 z; z.x = 0.0f; z.y = 0.0f;
    reinterpret_cast<float2*>(orow)[tid] = z;
    return;
  }
  int img = bm / MAX_SEGS;
  int f = finFeat[bm];
  const float* src = seg + ((size_t)(img * F + f)) * (FH * FW);

  // half-pixel-center bilinear, scale 4: src = (y+0.5)/4 - 0.5
  int yq = y >> 2, ry = y & 3;
  int y0 = (ry < 2) ? yq - 1 : yq;
  double wy0, wy1;
  switch (ry) {
    case 0: wy0 = 0.375; wy1 = 0.625; break;
    case 1: wy0 = 0.125; wy1 = 0.875; break;
    case 2: wy0 = 0.875; wy1 = 0.125; break;
    default: wy0 = 0.625; wy1 = 0.375; break;
  }
  int y1 = y0 + 1;
  if (y0 < 0)      { y0 = 0;      wy0 = 0.0; wy1 = 1.0; }  // edge renorm == single tap
  if (y1 > FH - 1) { y1 = FH - 1; wy1 = 0.0; wy0 = 1.0; }
  const float* r0p = src + (size_t)y0 * FW;
  const float* r1p = src + (size_t)y1 * FW;

  float vals[2];
#pragma unroll
  for (int e = 0; e < 2; ++e) {
    int x = tid * 2 + e;
    int xq = x >> 2, rx = x & 3;
    int x0 = (rx < 2) ? xq - 1 : xq;
    double wx0, wx1;
    switch (rx) {
      case 0: wx0 = 0.375; wx1 = 0.625; break;
      case 1: wx0 = 0.125; wx1 = 0.875; break;
      case 2: wx0 = 0.875; wx1 = 0.125; break;
      default: wx0 = 0.625; wx1 = 0.375; break;
    }
    int x1 = x0 + 1;
    if (x0 < 0)      { x0 = 0;      wx0 = 0.0; wx1 = 1.0; }
    if (x1 > FW - 1) { x1 = FW - 1; wx1 = 0.0; wx0 = 1.0; }
    double v00 = (double)r0p[x0], v01 = (double)r0p[x1];
    double v10 = (double)r1p[x0], v11 = (double)r1p[x1];
    double hv0 = wy0 * v00 + wy1 * v10;
    double hv1 = wy0 * v01 + wy1 * v11;
    double val = wx0 * hv0 + wx1 * hv1;
    vals[e] = (val > 0.0) ? 1.0f : 0.0f;
  }
  float2 res; res.x = vals[0]; res.y = vals[1];
  reinterpret_cast<float2*>(orow)[tid] = res;
}

// ---------------- host launch ----------------
extern "C" void kernel_launch(void* const* d_in, const int* in_sizes, int n_in,
                              void* d_out, int out_size, void* d_ws, size_t ws_size,
                              hipStream_t stream) {
  const float* cls = (const float*)d_in[0];
  const float* seg = (const float*)d_in[1];
  const int B = 2;  // fixed by setup_inputs
  int totalF = in_sizes[0] / NCLS1;      // 200
  int F = totalF / B;                    // 100

  float* out = (float*)d_out;
  // workspace layout
  float* boxes   = (float*)d_ws;                       // totalF*4 floats
  int*   validF  = (int*)(boxes + (size_t)totalF * 4); // totalF ints
  int*   finFeat = validF + totalF;                    // B*MAX_SEGS ints
  int*   finValid = finFeat + B * MAX_SEGS;            // B*MAX_SEGS ints

  const size_t labelsN   = (size_t)B * MAX_SEGS;             // 100
  const size_t maskElems = (size_t)B * MAX_SEGS * OH * OW;   // 26,214,400
  const size_t scoresOff = labelsN + maskElems;
  const size_t validOff  = scoresOff + labelsN;

  box_kernel<<<totalF, FH, 0, stream>>>(seg, boxes, validF);
  select_nms_kernel<<<B, 1024, 0, stream>>>(cls, boxes, validF, F, out,
                                            finFeat, finValid, scoresOff, validOff);
  interp_kernel<<<dim3(B * MAX_SEGS, OH), 256, 0, stream>>>(seg, finFeat, finValid,
                                                            out + labelsN, F);
}

// Round 3
// 101.070 us; speedup vs baseline: 1.9571x; 1.3460x over previous
//
#include <hip/hip_runtime.h>
#include <cstdint>
#include <cstddef>

#define NUM_CLASSES 80
#define NCLS1 81
#define NCAND 200
#define MAX_SEGS 50
#define FH 128
#define FW 128
#define NMS_THR 0.65f
#define CLS_OFFSET 129.0f
#define OH 512
#define OW 512
#define NBLK 8          // top-k blocks per image

typedef unsigned int u32;
typedef unsigned long long u64;
typedef float v4f __attribute__((ext_vector_type(4)));

__device__ __forceinline__ u32 ord_of_float(float f) {
  u32 u = __float_as_uint(f);
  return (u & 0x80000000u) ? ~u : (u | 0x80000000u);
}
__device__ __forceinline__ float float_of_ord(u32 o) {
  u32 u = (o & 0x80000000u) ? (o ^ 0x80000000u) : ~o;
  return __uint_as_float(u);
}

// ---------------- K1: per-feature mask validity + bounding box ----------------
// 256 threads: thread t owns float4-column (t&31), rows (t>>5)+8k. Vectorized.
__global__ void __launch_bounds__(256)
box_kernel(const float* __restrict__ seg,
           float* __restrict__ boxes, int* __restrict__ validF) {
  int f = blockIdx.x;
  int t = threadIdx.x;
  __shared__ u32 rowBits[4];
  __shared__ u32 colBits[4];
  if (t < 4) { rowBits[t] = 0; colBits[t] = 0; }
  __syncthreads();

  const v4f* base = reinterpret_cast<const v4f*>(seg + (size_t)f * (FH * FW));
  int c4 = t & 31;       // float4 column group (cols 4c4..4c4+3)
  int rbase = t >> 5;    // 0..7
  int lane = t & 63;
  bool cb0 = false, cb1 = false, cb2 = false, cb3 = false;
  u32 rb[4] = {0, 0, 0, 0};
#pragma unroll
  for (int it = 0; it < 16; ++it) {
    int r = rbase + (it << 3);
    v4f v = base[r * 32 + c4];
    bool p0 = v.x > 0.0f, p1 = v.y > 0.0f, p2 = v.z > 0.0f, p3 = v.w > 0.0f;
    cb0 |= p0; cb1 |= p1; cb2 |= p2; cb3 |= p3;
    u64 b = __ballot(p0 | p1 | p2 | p3);
    if (lane == 0) {
      // lanes 0-31 = row r (this thread's r), lanes 32-63 = row r+1
      if ((u32)b) rb[r >> 5] |= 1u << (r & 31);
      int r2 = r + 1;
      if ((u32)(b >> 32)) rb[r2 >> 5] |= 1u << (r2 & 31);
    }
  }
  if (lane == 0) {
#pragma unroll
    for (int w = 0; w < 4; ++w)
      if (rb[w]) atomicOr(&rowBits[w], rb[w]);
  }
  u32 nib = (u32)cb0 | ((u32)cb1 << 1) | ((u32)cb2 << 2) | ((u32)cb3 << 3);
  if (nib) atomicOr(&colBits[c4 >> 3], nib << ((c4 & 7) * 4));
  __syncthreads();

  if (t == 0) {
    int firstR = -1, lastR = -1;
    for (int w = 0; w < 4; ++w) {
      u32 b = rowBits[w];
      if (b) { if (firstR < 0) firstR = w * 32 + (__ffs(b) - 1); lastR = w * 32 + 31 - __clz((int)b); }
    }
    int firstC = -1, lastC = -1;
    for (int w = 0; w < 4; ++w) {
      u32 b = colBits[w];
      if (b) { if (firstC < 0) firstC = w * 32 + (__ffs(b) - 1); lastC = w * 32 + 31 - __clz((int)b); }
    }
    float x1, y1, x2, y2; int valid;
    if (firstR < 0) {
      valid = 0; x1 = 0.0f; y1 = 0.0f; x2 = (float)FW; y2 = (float)FH;
    } else {
      valid = 1;
      y1 = (float)firstR; y2 = (float)(lastR + 1);
      x1 = (float)firstC; x2 = (float)(lastC + 1);
    }
    boxes[f * 4 + 0] = x1; boxes[f * 4 + 1] = y1;
    boxes[f * 4 + 2] = x2; boxes[f * 4 + 3] = y2;
    validF[f] = valid;
  }
}

// ------- K2a: per-(image,chunk) fused score + local bitonic top-200 ----------
__global__ void __launch_bounds__(1024)
topk_local_kernel(const float* __restrict__ cls, const int* __restrict__ validF,
                  int F, u64* __restrict__ candWs) {
  int b = blockIdx.x;
  int img = b >> 3, blk = b & (NBLK - 1);
  int t = threadIdx.x;
  int NS = F * NUM_CLASSES;          // 8000
  int chunk = (NS + NBLK - 1) / NBLK; // 1000

  __shared__ u64 sk[1024];
  u64 key = 0;
  int idx = blk * chunk + t;
  if (t < chunk && idx < NS) {
    int f = idx / NUM_CLASSES, c = idx - f * NUM_CLASSES;
    int g = img * F + f;
    float logit = cls[(size_t)g * NCLS1 + c];
    float s = validF[g] ? (1.0f / (1.0f + expf(-logit))) : -1.0f;
    key = ((u64)ord_of_float(s) << 13) | (u64)(8191 - idx);  // all keys distinct
  }
  sk[t] = key;
  __syncthreads();

  // bitonic sort 1024 keys descending
  for (int k = 2; k <= 1024; k <<= 1) {
    for (int j = k >> 1; j > 0; j >>= 1) {
      int ixj = t ^ j;
      if (ixj > t) {
        u64 a = sk[t], bb = sk[ixj];
        bool desc = (t & k) == 0;
        if (desc ? (a < bb) : (a > bb)) { sk[t] = bb; sk[ixj] = a; }
      }
      __syncthreads();
    }
  }
  if (t < NCAND) candWs[(size_t)b * NCAND + t] = sk[t];
}

// ------- K2b: per-image merge (rank via binary search) + IoU + greedy NMS ----
__global__ void __launch_bounds__(1024)
merge_nms_kernel(const u64* __restrict__ candWs, const float* __restrict__ boxes,
                 int F, float* __restrict__ out,
                 int* __restrict__ finFeatWs, int* __restrict__ finValidWs,
                 size_t scoresOff, size_t validOff) {
  const int img = blockIdx.x;
  const int tid = threadIdx.x;
  const int NTOT = NBLK * NCAND;  // 1600

  __shared__ u64 sk[NBLK * NCAND];
  __shared__ float candScore[NCAND];
  __shared__ int candFeat[NCAND], candLabel[NCAND];
  __shared__ float candBox[NCAND][4];
  __shared__ u64 supp[NCAND][4];
  __shared__ int keepFlag[NCAND];
  __shared__ int finFeat[MAX_SEGS], finLabel[MAX_SEGS], finValid[MAX_SEGS];
  __shared__ float finScore[MAX_SEGS];

  for (int i = tid; i < NTOT; i += 1024) sk[i] = candWs[(size_t)img * NTOT + i];
  for (int i = tid; i < NCAND * 4; i += 1024) supp[i >> 2][i & 3] = 0;
  __syncthreads();

  // rank = #keys strictly greater (keys distinct -> unique dense ranks)
  for (int i = tid; i < NTOT; i += 1024) {
    u64 k = sk[i];
    int rank = 0;
#pragma unroll
    for (int l = 0; l < NBLK; ++l) {
      const u64* arr = &sk[l * NCAND];
      int lo = 0, hi = NCAND;
      while (lo < hi) {
        int mid = (lo + hi) >> 1;
        if (arr[mid] > k) lo = mid + 1; else hi = mid;
      }
      rank += lo;
    }
    if (rank < NCAND) {
      int idx = 8191 - (int)(k & 0x1FFF);
      u32 o = (u32)(k >> 13);
      int f = idx / NUM_CLASSES, c = idx - f * NUM_CLASSES;
      float sc = float_of_ord(o);
      float off = (float)c * CLS_OFFSET;
      int g = img * F + f;
      candScore[rank] = sc; candFeat[rank] = f; candLabel[rank] = c;
      candBox[rank][0] = boxes[g * 4 + 0] + off;
      candBox[rank][1] = boxes[g * 4 + 1] + off;
      candBox[rank][2] = boxes[g * 4 + 2] + off;
      candBox[rank][3] = boxes[g * 4 + 3] + off;
    }
  }
  __syncthreads();

  // pairwise IoU, folded triangular indexing: 19900 pairs (j < i)
  for (int p = tid; p < (NCAND * (NCAND - 1)) / 2; p += 1024) {
    int r = p / (NCAND / 2), cc = p - r * (NCAND / 2);
    int i, j;
    if (cc <= r) { i = r + 1; j = cc; }
    else         { i = NCAND - 1 - r; j = NCAND - 1 - cc; }
    float ax1 = candBox[i][0], ay1 = candBox[i][1], ax2 = candBox[i][2], ay2 = candBox[i][3];
    float bx1 = candBox[j][0], by1 = candBox[j][1], bx2 = candBox[j][2], by2 = candBox[j][3];
    float areaA = (ax2 - ax1) * (ay2 - ay1);
    float areaB = (bx2 - bx1) * (by2 - by1);
    float lx = fmaxf(ax1, bx1), ly = fmaxf(ay1, by1);
    float rx = fminf(ax2, bx2), ry = fminf(ay2, by2);
    float w = fmaxf(rx - lx, 0.0f), h = fmaxf(ry - ly, 0.0f);
    float inter = w * h;
    float iou = inter / ((areaA + areaB - inter) + 1e-9f);
    if (iou > NMS_THR) atomicOr(&supp[i][j >> 6], 1ull << (j & 63));
  }
  __syncthreads();

  // serial greedy NMS (pipelined) + final top-50
  if (tid == 0) {
    u64 k0 = 0, k1 = 0, k2 = 0, k3 = 0;
    int nf = 0;
    u64 n0 = supp[0][0], n1 = supp[0][1], n2 = supp[0][2], n3 = supp[0][3];
    float nsc = candScore[0];
    for (int i = 0; i < NCAND; ++i) {
      u64 r0 = n0, r1 = n1, r2 = n2, r3 = n3;
      float sc = nsc;
      if (i + 1 < NCAND) {
        n0 = supp[i + 1][0]; n1 = supp[i + 1][1];
        n2 = supp[i + 1][2]; n3 = supp[i + 1][3];
        nsc = candScore[i + 1];
      }
      bool valid_i = sc > -0.5f;
      bool sup = ((r0 & k0) | (r1 & k1) | (r2 & k2) | (r3 & k3)) != 0ull;
      if (valid_i && !sup) {
        u64 bit = 1ull << (i & 63);
        if (i < 64) k0 |= bit; else if (i < 128) k1 |= bit;
        else if (i < 192) k2 |= bit; else k3 |= bit;
        keepFlag[i] = 1;
        if (nf < MAX_SEGS) {
          finFeat[nf] = candFeat[i]; finLabel[nf] = candLabel[i];
          finScore[nf] = sc; finValid[nf] = 1; ++nf;
        }
      } else {
        keepFlag[i] = 0;
      }
    }
    for (int i = 0; i < NCAND && nf < MAX_SEGS; ++i) {
      if (!keepFlag[i]) {
        finFeat[nf] = candFeat[i]; finLabel[nf] = candLabel[i];
        finScore[nf] = candScore[i]; finValid[nf] = 0; ++nf;
      }
    }
  }
  __syncthreads();

  if (tid < MAX_SEGS) {
    int o = img * MAX_SEGS + tid;
    out[o] = (float)finLabel[tid];
    out[scoresOff + (size_t)o] = finValid[tid] ? finScore[tid] : 0.0f;
    out[validOff + (size_t)o] = finValid[tid] ? 1.0f : 0.0f;
    finFeatWs[o] = finFeat[tid];
    finValidWs[o] = finValid[tid];
  }
}

// ---------------- K3: bilinear 128->512 upsample + threshold ----------------
// 256 threads = 2 output rows, thread -> 4 consecutive px, float4 NT store.
__global__ void __launch_bounds__(256)
interp_kernel(const float* __restrict__ seg, const int* __restrict__ finFeat,
              const int* __restrict__ finValid, float* __restrict__ outMasks, int F) {
  int bm = blockIdx.x;                      // img*MAX_SEGS + m
  int tid = threadIdx.x;
  int y = blockIdx.y * 2 + (tid >> 7);      // output row
  int q = tid & 127;                        // float4 group -> cols 4q..4q+3
  v4f* orow = reinterpret_cast<v4f*>(outMasks + (size_t)bm * (OH * OW) + (size_t)y * OW);

  if (!finValid[bm]) {
    v4f z = {0.0f, 0.0f, 0.0f, 0.0f};
    __builtin_nontemporal_store(z, &orow[q]);
    return;
  }
  int img = bm / MAX_SEGS;
  int f = finFeat[bm];
  const float* src = seg + ((size_t)(img * F + f)) * (FH * FW);

  // vertical: half-pixel centers, scale 4 (weight-zeroing at edges is exact)
  int yq = y >> 2, ry = y & 3;
  int y0 = (ry < 2) ? yq - 1 : yq;
  double wy0, wy1;
  switch (ry) {
    case 0: wy0 = 0.375; wy1 = 0.625; break;
    case 1: wy0 = 0.125; wy1 = 0.875; break;
    case 2: wy0 = 0.875; wy1 = 0.125; break;
    default: wy0 = 0.625; wy1 = 0.375; break;
  }
  int y1 = y0 + 1;
  if (y0 < 0)      { y0 = 0;      wy0 = 0.0; wy1 = 1.0; }
  if (y1 > FH - 1) { y1 = FH - 1; wy1 = 0.0; wy0 = 1.0; }
  const float* r0p = src + (size_t)y0 * FW;
  const float* r1p = src + (size_t)y1 * FW;

  int qm = (q > 0) ? q - 1 : 0;
  int qp = (q < FW - 1) ? q + 1 : FW - 1;
  double a0 = (double)r0p[qm], b0 = (double)r0p[q], c0 = (double)r0p[qp];
  double a1 = (double)r1p[qm], b1 = (double)r1p[q], c1 = (double)r1p[qp];
  double A = wy0 * a0 + wy1 * a1;
  double B = wy0 * b0 + wy1 * b1;
  double C = wy0 * c0 + wy1 * c1;

  // horizontal: px taps for x = 4q+{0,1,2,3} are (A,B),(A,B),(B,C),(B,C);
  // at q==0 or q==127 the ref collapses to single-tap == B exactly.
  double px0 = (q == 0) ? B : (0.375 * A + 0.625 * B);
  double px1 = (q == 0) ? B : (0.125 * A + 0.875 * B);
  double px2 = (q == FW - 1) ? B : (0.875 * B + 0.125 * C);
  double px3 = (q == FW - 1) ? B : (0.625 * B + 0.375 * C);

  v4f res;
  res.x = (px0 > 0.0) ? 1.0f : 0.0f;
  res.y = (px1 > 0.0) ? 1.0f : 0.0f;
  res.z = (px2 > 0.0) ? 1.0f : 0.0f;
  res.w = (px3 > 0.0) ? 1.0f : 0.0f;
  __builtin_nontemporal_store(res, &orow[q]);
}

// ---------------- host launch ----------------
extern "C" void kernel_launch(void* const* d_in, const int* in_sizes, int n_in,
                              void* d_out, int out_size, void* d_ws, size_t ws_size,
                              hipStream_t stream) {
  const float* cls = (const float*)d_in[0];
  const float* seg = (const float*)d_in[1];
  const int B = 2;  // fixed by setup_inputs
  int totalF = in_sizes[0] / NCLS1;      // 200
  int F = totalF / B;                    // 100

  float* out = (float*)d_out;
  // workspace layout (u64 first for alignment)
  u64*   candWs  = (u64*)d_ws;                             // B*8*200 u64
  float* boxes   = (float*)(candWs + (size_t)B * NBLK * NCAND);
  int*   validF  = (int*)(boxes + (size_t)totalF * 4);
  int*   finFeat = validF + totalF;
  int*   finValid = finFeat + B * MAX_SEGS;

  const size_t labelsN   = (size_t)B * MAX_SEGS;             // 100
  const size_t maskElems = (size_t)B * MAX_SEGS * OH * OW;   // 26,214,400
  const size_t scoresOff = labelsN + maskElems;
  const size_t validOff  = scoresOff + labelsN;

  box_kernel<<<totalF, 256, 0, stream>>>(seg, boxes, validF);
  topk_local_kernel<<<B * NBLK, 1024, 0, stream>>>(cls, validF, F, candWs);
  merge_nms_kernel<<<B, 1024, 0, stream>>>(candWs, boxes, F, out,
                                           finFeat, finValid, scoresOff, validOff);
  interp_kernel<<<dim3(B * MAX_SEGS, OH / 2), 256, 0, stream>>>(seg, finFeat, finValid,
                                                                out + labelsN, F);
}

// Round 4
// 86.862 us; speedup vs baseline: 2.2772x; 1.1636x over previous
//
#include <hip/hip_runtime.h>
#include <cstdint>
#include <cstddef>

#define NUM_CLASSES 80
#define NCLS1 81
#define NCAND 200
#define MAX_SEGS 50
#define FH 128
#define FW 128
#define NMS_THR 0.65f
#define CLS_OFFSET 129.0f
#define OH 512
#define OW 512
#define NBLK 8          // top-k blocks per image

typedef unsigned int u32;
typedef unsigned long long u64;
typedef float v4f __attribute__((ext_vector_type(4)));

__device__ __forceinline__ u32 ord_of_float(float f) {
  u32 u = __float_as_uint(f);
  return (u & 0x80000000u) ? ~u : (u | 0x80000000u);
}
__device__ __forceinline__ float float_of_ord(u32 o) {
  u32 u = (o & 0x80000000u) ? (o ^ 0x80000000u) : ~o;
  return __uint_as_float(u);
}

// ---------------- K1: per-feature mask validity + bounding box ----------------
__global__ void __launch_bounds__(256)
box_kernel(const float* __restrict__ seg,
           float* __restrict__ boxes, int* __restrict__ validF) {
  int f = blockIdx.x;
  int t = threadIdx.x;
  __shared__ u32 rowBits[4];
  __shared__ u32 colBits[4];
  if (t < 4) { rowBits[t] = 0; colBits[t] = 0; }
  __syncthreads();

  const v4f* base = reinterpret_cast<const v4f*>(seg + (size_t)f * (FH * FW));
  int c4 = t & 31;
  int rbase = t >> 5;
  int lane = t & 63;
  bool cb0 = false, cb1 = false, cb2 = false, cb3 = false;
  u32 rb[4] = {0, 0, 0, 0};
#pragma unroll
  for (int it = 0; it < 16; ++it) {
    int r = rbase + (it << 3);
    v4f v = base[r * 32 + c4];
    bool p0 = v.x > 0.0f, p1 = v.y > 0.0f, p2 = v.z > 0.0f, p3 = v.w > 0.0f;
    cb0 |= p0; cb1 |= p1; cb2 |= p2; cb3 |= p3;
    u64 b = __ballot(p0 | p1 | p2 | p3);
    if (lane == 0) {
      if ((u32)b) rb[r >> 5] |= 1u << (r & 31);
      int r2 = r + 1;
      if ((u32)(b >> 32)) rb[r2 >> 5] |= 1u << (r2 & 31);
    }
  }
  if (lane == 0) {
#pragma unroll
    for (int w = 0; w < 4; ++w)
      if (rb[w]) atomicOr(&rowBits[w], rb[w]);
  }
  u32 nib = (u32)cb0 | ((u32)cb1 << 1) | ((u32)cb2 << 2) | ((u32)cb3 << 3);
  if (nib) atomicOr(&colBits[c4 >> 3], nib << ((c4 & 7) * 4));
  __syncthreads();

  if (t == 0) {
    int firstR = -1, lastR = -1;
    for (int w = 0; w < 4; ++w) {
      u32 b = rowBits[w];
      if (b) { if (firstR < 0) firstR = w * 32 + (__ffs(b) - 1); lastR = w * 32 + 31 - __clz((int)b); }
    }
    int firstC = -1, lastC = -1;
    for (int w = 0; w < 4; ++w) {
      u32 b = colBits[w];
      if (b) { if (firstC < 0) firstC = w * 32 + (__ffs(b) - 1); lastC = w * 32 + 31 - __clz((int)b); }
    }
    float x1, y1, x2, y2; int valid;
    if (firstR < 0) {
      valid = 0; x1 = 0.0f; y1 = 0.0f; x2 = (float)FW; y2 = (float)FH;
    } else {
      valid = 1;
      y1 = (float)firstR; y2 = (float)(lastR + 1);
      x1 = (float)firstC; x2 = (float)(lastC + 1);
    }
    boxes[f * 4 + 0] = x1; boxes[f * 4 + 1] = y1;
    boxes[f * 4 + 2] = x2; boxes[f * 4 + 3] = y2;
    validF[f] = valid;
  }
}

// ------- K2a: fused score + hybrid (shfl/LDS) bitonic local top-200 ----------
__global__ void __launch_bounds__(1024)
topk_local_kernel(const float* __restrict__ cls, const int* __restrict__ validF,
                  int F, u64* __restrict__ candWs) {
  int b = blockIdx.x;
  int img = b >> 3, blk = b & (NBLK - 1);
  int t = threadIdx.x;
  int lane = t & 63;
  int NS = F * NUM_CLASSES;            // 8000
  int chunk = NS / NBLK;               // 1000

  __shared__ u64 xb[2][1024];
  u64 key = 0;
  int idx = blk * chunk + t;
  if (t < chunk) {
    int f = idx / NUM_CLASSES, c = idx - f * NUM_CLASSES;
    int g = img * F + f;
    float logit = cls[(size_t)g * NCLS1 + c];
    float s = validF[g] ? (1.0f / (1.0f + expf(-logit))) : -1.0f;
    key = ((u64)ord_of_float(s) << 13) | (u64)(8191 - idx);  // all keys distinct, nonzero
  }

  int pb = 0;
  for (int k = 2; k <= 1024; k <<= 1) {
    for (int j = k >> 1; j > 0; j >>= 1) {
      u64 px;
      bool lower;
      if (j <= 32) {
        px = __shfl_xor(key, j);
        lower = (lane & j) == 0;
      } else {
        xb[pb][t] = key;
        __syncthreads();
        px = xb[pb][t ^ j];
        pb ^= 1;
        lower = (t & j) == 0;
      }
      bool desc = (t & k) == 0;
      u64 mn = key < px ? key : px;
      u64 mx = key < px ? px : key;
      key = (lower == desc) ? mx : mn;
    }
  }
  if (t < NCAND) candWs[(size_t)b * NCAND + t] = key;   // rank t directly from register
}

// ------- K2b: per-image merge (rank via binary search) + IoU + greedy NMS ----
__global__ void __launch_bounds__(1024)
merge_nms_kernel(const u64* __restrict__ candWs, const float* __restrict__ boxes,
                 int F, float* __restrict__ out,
                 int* __restrict__ finFeatWs, int* __restrict__ finValidWs,
                 size_t scoresOff, size_t validOff) {
  const int img = blockIdx.x;
  const int tid = threadIdx.x;
  const int NTOT = NBLK * NCAND;  // 1600

  __shared__ u64 sk[NBLK * NCAND];
  __shared__ float candScore[NCAND];
  __shared__ int candFeat[NCAND], candLabel[NCAND];
  __shared__ float candBox[NCAND][4];
  __shared__ u64 supp[NCAND][4];
  __shared__ int finIdx[MAX_SEGS];
  __shared__ int finCnt;

  for (int i = tid; i < NTOT; i += 1024) sk[i] = candWs[(size_t)img * NTOT + i];
  for (int i = tid; i < NCAND * 4; i += 1024) supp[i >> 2][i & 3] = 0;
  __syncthreads();

  // rank = #keys strictly greater (keys distinct -> unique dense ranks)
  for (int i = tid; i < NTOT; i += 1024) {
    u64 k = sk[i];
    int rank = 0;
#pragma unroll
    for (int l = 0; l < NBLK; ++l) {
      const u64* arr = &sk[l * NCAND];
      int lo = 0, hi = NCAND;
      while (lo < hi) {
        int mid = (lo + hi) >> 1;
        if (arr[mid] > k) lo = mid + 1; else hi = mid;
      }
      rank += lo;
    }
    if (rank < NCAND) {
      int idx = 8191 - (int)(k & 0x1FFF);
      u32 o = (u32)(k >> 13);
      int f = idx / NUM_CLASSES, c = idx - f * NUM_CLASSES;
      float sc = float_of_ord(o);
      float off = (float)c * CLS_OFFSET;
      int g = img * F + f;
      candScore[rank] = sc; candFeat[rank] = f; candLabel[rank] = c;
      candBox[rank][0] = boxes[g * 4 + 0] + off;
      candBox[rank][1] = boxes[g * 4 + 1] + off;
      candBox[rank][2] = boxes[g * 4 + 2] + off;
      candBox[rank][3] = boxes[g * 4 + 3] + off;
    }
  }
  __syncthreads();

  // pairwise IoU, folded triangular indexing: 19900 pairs (j < i)
  for (int p = tid; p < (NCAND * (NCAND - 1)) / 2; p += 1024) {
    int r = p / (NCAND / 2), cc = p - r * (NCAND / 2);
    int i, j;
    if (cc <= r) { i = r + 1; j = cc; }
    else         { i = NCAND - 1 - r; j = NCAND - 1 - cc; }
    float ax1 = candBox[i][0], ay1 = candBox[i][1], ax2 = candBox[i][2], ay2 = candBox[i][3];
    float bx1 = candBox[j][0], by1 = candBox[j][1], bx2 = candBox[j][2], by2 = candBox[j][3];
    float areaA = (ax2 - ax1) * (ay2 - ay1);
    float areaB = (bx2 - bx1) * (by2 - by1);
    float lx = fmaxf(ax1, bx1), ly = fmaxf(ay1, by1);
    float rx = fminf(ax2, bx2), ry = fminf(ay2, by2);
    float w = fmaxf(rx - lx, 0.0f), h = fmaxf(ry - ly, 0.0f);
    float inter = w * h;
    float iou = inter / ((areaA + areaB - inter) + 1e-9f);
    if (iou > NMS_THR) atomicOr(&supp[i][j >> 6], 1ull << (j & 63));
  }
  __syncthreads();

  // serial greedy NMS, depth-4 software pipeline, keep-mask in registers
  if (tid == 0) {
    u64 ka = 0, kb = 0, kc = 0, kd = 0;
    int nf = 0;
    u64 A0, A1, A2, A3, B0, B1, B2, B3, C0, C1, C2, C3, D0, D1, D2, D3;
    float sA, sB, sC, sD;
#define LOADR(S0, S1, S2, S3, SS, ii) \
    { S0 = supp[ii][0]; S1 = supp[ii][1]; S2 = supp[ii][2]; S3 = supp[ii][3]; SS = candScore[ii]; }
#define PROCR(S0, S1, S2, S3, SS, ii) \
    { bool sup = ((S0 & ka) | (S1 & kb) | (S2 & kc) | (S3 & kd)) != 0ull;      \
      if ((SS > -0.5f) && !sup) {                                              \
        u64 bit = 1ull << ((ii) & 63);                                         \
        if ((ii) < 64) ka |= bit; else if ((ii) < 128) kb |= bit;              \
        else if ((ii) < 192) kc |= bit; else kd |= bit;                        \
        if (nf < MAX_SEGS) finIdx[nf] = (ii);                                  \
        ++nf; } }
    LOADR(A0, A1, A2, A3, sA, 0)
    LOADR(B0, B1, B2, B3, sB, 1)
    LOADR(C0, C1, C2, C3, sC, 2)
    LOADR(D0, D1, D2, D3, sD, 3)
    for (int i = 0; i < NCAND; i += 4) {
      PROCR(A0, A1, A2, A3, sA, i)
      if (i + 4 < NCAND) LOADR(A0, A1, A2, A3, sA, i + 4)
      PROCR(B0, B1, B2, B3, sB, i + 1)
      if (i + 5 < NCAND) LOADR(B0, B1, B2, B3, sB, i + 5)
      PROCR(C0, C1, C2, C3, sC, i + 2)
      if (i + 6 < NCAND) LOADR(C0, C1, C2, C3, sC, i + 6)
      PROCR(D0, D1, D2, D3, sD, i + 3)
      if (i + 7 < NCAND) LOADR(D0, D1, D2, D3, sD, i + 7)
    }
    int m = nf < MAX_SEGS ? nf : MAX_SEGS;
    finCnt = m;
    for (int i = 0; i < NCAND && m < MAX_SEGS; ++i) {
      u64 w = (i < 64) ? ka : (i < 128) ? kb : (i < 192) ? kc : kd;
      if (!((w >> (i & 63)) & 1ull)) finIdx[m++] = i;
    }
#undef LOADR
#undef PROCR
  }
  __syncthreads();

  if (tid < MAX_SEGS) {
    int keptN = finCnt;
    int i = finIdx[tid];
    bool v = tid < keptN;
    int o = img * MAX_SEGS + tid;
    out[o] = (float)candLabel[i];
    out[scoresOff + (size_t)o] = v ? candScore[i] : 0.0f;
    out[validOff + (size_t)o] = v ? 1.0f : 0.0f;
    finFeatWs[o] = candFeat[i];
    finValidWs[o] = v ? 1 : 0;
  }
}

// ---------------- K3: bilinear 128->512 upsample + threshold ----------------
// 256 threads = 2 src-row quads x 128 col-groups; thread -> 4 rows x 4 px.
__global__ void __launch_bounds__(256)
interp_kernel(const float* __restrict__ seg, const int* __restrict__ finFeat,
              const int* __restrict__ finValid, float* __restrict__ outMasks, int F) {
  int bm = blockIdx.x;
  int tid = threadIdx.x;
  int q = tid & 127;                        // col group -> cols 4q..4q+3
  int Q = blockIdx.y * 2 + (tid >> 7);      // src quad -> output rows 4Q..4Q+3
  float* obase = outMasks + (size_t)bm * (OH * OW) + (size_t)(4 * Q) * OW;

  if (!finValid[bm]) {
    v4f z = {0.0f, 0.0f, 0.0f, 0.0f};
#pragma unroll
    for (int r = 0; r < 4; ++r)
      __builtin_nontemporal_store(z, reinterpret_cast<v4f*>(obase + r * OW) + q);
    return;
  }
  int img = bm / MAX_SEGS;
  int f = finFeat[bm];
  const float* src = seg + ((size_t)(img * F + f)) * (FH * FW);

  int rm = (Q > 0) ? Q - 1 : 0;
  int rp = (Q < FH / 4 * 4 / 4 * 4 - 1 && Q < 127) ? Q + 1 : 127;
  const float* prm = src + (size_t)rm * FW;
  const float* pr0 = src + (size_t)Q * FW;
  const float* prp = src + (size_t)rp * FW;
  int qm = (q > 0) ? q - 1 : 0;
  int qp = (q < FW - 1) ? q + 1 : FW - 1;

  double am = prm[qm], a0 = pr0[qm], ap = prp[qm];
  double bmv = prm[q], b0 = pr0[q], bp = prp[q];
  double cm = prm[qp], c0 = pr0[qp], cp = prp[qp];

  // vertical blend per ry (ry0/1 use rows Q-1,Q; ry2/3 use rows Q,Q+1)
  double A[4], Bv[4], C[4];
  if (Q == 0) {
    A[0] = a0; Bv[0] = b0; C[0] = c0;
    A[1] = a0; Bv[1] = b0; C[1] = c0;
  } else {
    A[0] = 0.375 * am + 0.625 * a0;  Bv[0] = 0.375 * bmv + 0.625 * b0;  C[0] = 0.375 * cm + 0.625 * c0;
    A[1] = 0.125 * am + 0.875 * a0;  Bv[1] = 0.125 * bmv + 0.875 * b0;  C[1] = 0.125 * cm + 0.875 * c0;
  }
  if (Q == 127) {
    A[2] = a0; Bv[2] = b0; C[2] = c0;
    A[3] = a0; Bv[3] = b0; C[3] = c0;
  } else {
    A[2] = 0.875 * a0 + 0.125 * ap;  Bv[2] = 0.875 * b0 + 0.125 * bp;  C[2] = 0.875 * c0 + 0.125 * cp;
    A[3] = 0.625 * a0 + 0.375 * ap;  Bv[3] = 0.625 * b0 + 0.375 * bp;  C[3] = 0.625 * c0 + 0.375 * cp;
  }

#pragma unroll
  for (int r = 0; r < 4; ++r) {
    double px0 = (q == 0)      ? Bv[r] : (0.375 * A[r] + 0.625 * Bv[r]);
    double px1 = (q == 0)      ? Bv[r] : (0.125 * A[r] + 0.875 * Bv[r]);
    double px2 = (q == FW - 1) ? Bv[r] : (0.875 * Bv[r] + 0.125 * C[r]);
    double px3 = (q == FW - 1) ? Bv[r] : (0.625 * Bv[r] + 0.375 * C[r]);
    v4f res;
    res.x = (px0 > 0.0) ? 1.0f : 0.0f;
    res.y = (px1 > 0.0) ? 1.0f : 0.0f;
    res.z = (px2 > 0.0) ? 1.0f : 0.0f;
    res.w = (px3 > 0.0) ? 1.0f : 0.0f;
    __builtin_nontemporal_store(res, reinterpret_cast<v4f*>(obase + r * OW) + q);
  }
}

// ---------------- host launch ----------------
extern "C" void kernel_launch(void* const* d_in, const int* in_sizes, int n_in,
                              void* d_out, int out_size, void* d_ws, size_t ws_size,
                              hipStream_t stream) {
  const float* cls = (const float*)d_in[0];
  const float* seg = (const float*)d_in[1];
  const int B = 2;  // fixed by setup_inputs
  int totalF = in_sizes[0] / NCLS1;      // 200
  int F = totalF / B;                    // 100

  float* out = (float*)d_out;
  u64*   candWs  = (u64*)d_ws;                             // B*8*200 u64
  float* boxes   = (float*)(candWs + (size_t)B * NBLK * NCAND);
  int*   validF  = (int*)(boxes + (size_t)totalF * 4);
  int*   finFeat = validF + totalF;
  int*   finValid = finFeat + B * MAX_SEGS;

  const size_t labelsN   = (size_t)B * MAX_SEGS;             // 100
  const size_t maskElems = (size_t)B * MAX_SEGS * OH * OW;   // 26,214,400
  const size_t scoresOff = labelsN + maskElems;
  const size_t validOff  = scoresOff + labelsN;

  box_kernel<<<totalF, 256, 0, stream>>>(seg, boxes, validF);
  topk_local_kernel<<<B * NBLK, 1024, 0, stream>>>(cls, validF, F, candWs);
  merge_nms_kernel<<<B, 1024, 0, stream>>>(candWs, boxes, F, out,
                                           finFeat, finValid, scoresOff, validOff);
  interp_kernel<<<dim3(B * MAX_SEGS, OH / 8), 256, 0, stream>>>(seg, finFeat, finValid,
                                                                out + labelsN, F);
}

// Round 5
// 77.796 us; speedup vs baseline: 2.5426x; 1.1165x over previous
//
#include <hip/hip_runtime.h>
#include <cstdint>
#include <cstddef>

#define NUM_CLASSES 80
#define NCLS1 81
#define NCAND 200
#define MAX_SEGS 50
#define FH 128
#define FW 128
#define NMS_THR 0.65f
#define CLS_OFFSET 129.0f
#define OH 512
#define OW 512

typedef unsigned int u32;
typedef unsigned long long u64;
typedef float v4f __attribute__((ext_vector_type(4)));

__device__ __forceinline__ u32 ord_of_float(float f) {
  u32 u = __float_as_uint(f);
  return (u & 0x80000000u) ? ~u : (u | 0x80000000u);
}
__device__ __forceinline__ float float_of_ord(u32 o) {
  u32 u = (o & 0x80000000u) ? (o ^ 0x80000000u) : ~o;
  return __uint_as_float(u);
}

// ---------------- K1: per-feature mask validity + bounding box ----------------
__global__ void __launch_bounds__(256)
box_kernel(const float* __restrict__ seg,
           float* __restrict__ boxes, int* __restrict__ validF) {
  int f = blockIdx.x;
  int t = threadIdx.x;
  __shared__ u32 rowBits[4];
  __shared__ u32 colBits[4];
  if (t < 4) { rowBits[t] = 0; colBits[t] = 0; }
  __syncthreads();

  const v4f* base = reinterpret_cast<const v4f*>(seg + (size_t)f * (FH * FW));
  int c4 = t & 31;
  int rbase = t >> 5;
  int lane = t & 63;
  bool cb0 = false, cb1 = false, cb2 = false, cb3 = false;
  u32 rb[4] = {0, 0, 0, 0};
#pragma unroll
  for (int it = 0; it < 16; ++it) {
    int r = rbase + (it << 3);
    v4f v = base[r * 32 + c4];
    bool p0 = v.x > 0.0f, p1 = v.y > 0.0f, p2 = v.z > 0.0f, p3 = v.w > 0.0f;
    cb0 |= p0; cb1 |= p1; cb2 |= p2; cb3 |= p3;
    u64 b = __ballot(p0 | p1 | p2 | p3);
    if (lane == 0) {
      if ((u32)b) rb[r >> 5] |= 1u << (r & 31);
      int r2 = r + 1;
      if ((u32)(b >> 32)) rb[r2 >> 5] |= 1u << (r2 & 31);
    }
  }
  if (lane == 0) {
#pragma unroll
    for (int w = 0; w < 4; ++w)
      if (rb[w]) atomicOr(&rowBits[w], rb[w]);
  }
  u32 nib = (u32)cb0 | ((u32)cb1 << 1) | ((u32)cb2 << 2) | ((u32)cb3 << 3);
  if (nib) atomicOr(&colBits[c4 >> 3], nib << ((c4 & 7) * 4));
  __syncthreads();

  if (t == 0) {
    int firstR = -1, lastR = -1;
    for (int w = 0; w < 4; ++w) {
      u32 b = rowBits[w];
      if (b) { if (firstR < 0) firstR = w * 32 + (__ffs(b) - 1); lastR = w * 32 + 31 - __clz((int)b); }
    }
    int firstC = -1, lastC = -1;
    for (int w = 0; w < 4; ++w) {
      u32 b = colBits[w];
      if (b) { if (firstC < 0) firstC = w * 32 + (__ffs(b) - 1); lastC = w * 32 + 31 - __clz((int)b); }
    }
    float x1, y1, x2, y2; int valid;
    if (firstR < 0) {
      valid = 0; x1 = 0.0f; y1 = 0.0f; x2 = (float)FW; y2 = (float)FH;
    } else {
      valid = 1;
      y1 = (float)firstR; y2 = (float)(lastR + 1);
      x1 = (float)firstC; x2 = (float)(lastC + 1);
    }
    boxes[f * 4 + 0] = x1; boxes[f * 4 + 1] = y1;
    boxes[f * 4 + 2] = x2; boxes[f * 4 + 3] = y2;
    validF[f] = valid;
  }
}

// ---- K2: fused exact top-200 (register radix descent) + IoU + greedy NMS ----
__global__ void __launch_bounds__(1024)
select_nms_kernel(const float* __restrict__ cls, const float* __restrict__ boxes,
                  const int* __restrict__ validF, int F,
                  float* __restrict__ out,
                  int* __restrict__ finFeatWs, int* __restrict__ finValidWs,
                  size_t scoresOff, size_t validOff) {
  const int img = blockIdx.x;
  const int tid = threadIdx.x;
  const int NS = F * NUM_CLASSES;  // 8000

  __shared__ u32 hist[2048];
  __shared__ u64 gk[1024];
  __shared__ int cntG;
  __shared__ u64 sPrefix;
  __shared__ int sR, sDone;
  __shared__ float candScore[NCAND];
  __shared__ int candFeat[NCAND], candLabel[NCAND];
  __shared__ float candBox[NCAND][4];
  __shared__ u64 supp[NCAND][4];
  __shared__ int finIdx[MAX_SEGS];
  __shared__ int finCnt;

  // (a) build keys in registers: 8/thread
  u64 rkey[8];
#pragma unroll
  for (int p = 0; p < 8; ++p) {
    int idx = tid + (p << 10);
    u64 key = 0;
    if (idx < NS) {
      int f = idx / NUM_CLASSES, c = idx - f * NUM_CLASSES;
      int g = img * F + f;
      float logit = cls[(size_t)g * NCLS1 + c];
      float s = validF[g] ? (1.0f / (1.0f + expf(-logit))) : -1.0f;
      key = ((u64)ord_of_float(s) << 13) | (u64)(8191 - idx);  // distinct, nonzero
    }
    rkey[p] = key;
  }
  if (tid == 0) { sPrefix = 0; sR = NCAND; sDone = 0; cntG = 0; }

  // (b) 2048-way radix descent over key bits (45-bit keys), usually 1 level
  const int shifts[4] = {34, 23, 12, 1};
  int fsh = 1;
  for (int lev = 0; lev < 4; ++lev) {
    int shift = shifts[lev];
    for (int i = tid; i < 2048; i += 1024) hist[i] = 0;
    __syncthreads();
    u64 pf = sPrefix;
    int R = sR;
#pragma unroll
    for (int p = 0; p < 8; ++p) {
      int idx = tid + (p << 10);
      u64 k = rkey[p];
      if (idx < NS && (k >> (shift + 11)) == pf)
        atomicAdd(&hist[(k >> shift) & 2047], 1u);
    }
    __syncthreads();
    if (tid < 64) {
      int lane = tid;
      u32 lsum = 0;
      for (int b = 0; b < 32; ++b) lsum += hist[lane * 32 + b];
      u32 suf = lsum;
#pragma unroll
      for (int d = 1; d < 64; d <<= 1) {
        u32 o = __shfl_down(suf, d);
        if (lane + d < 64) suf += o;
      }
      u32 above = suf - lsum;               // bins >= (lane+1)*32
      if (above < (u32)R && suf >= (u32)R) {
        u32 cum = above; int vb = 0; u32 hv = 0;
        for (int b = 31; b >= 0; --b) {
          u32 hb = hist[lane * 32 + b];
          if (cum + hb >= (u32)R) { vb = lane * 32 + b; hv = hb; break; }
          cum += hb;
        }
        int newR = R - (int)cum;
        sPrefix = (pf << 11) | (u64)vb;
        sR = newR;
        if ((NCAND - newR) + (int)hv <= 1024) sDone = 1;
      }
    }
    __syncthreads();
    if (sDone) { fsh = shift; break; }
  }
  u64 fpfx = sPrefix;

  // (c) gather all keys with (key>>fsh) >= fpfx  (200 <= count <= 1024)
#pragma unroll
  for (int p = 0; p < 8; ++p) {
    int idx = tid + (p << 10);
    u64 k = rkey[p];
    if (idx < NS && (k >> fsh) >= fpfx) {
      int pos = atomicAdd(&cntG, 1);
      if (pos < 1024) gk[pos] = k;
    }
  }
  for (int i = tid; i < NCAND * 4; i += 1024) supp[i >> 2][i & 3] = 0;
  __syncthreads();
  int n = cntG < 1024 ? cntG : 1024;

  // (d) exact rank among gathered (distinct keys -> dense unique ranks)
  if (tid < n) {
    u64 k = gk[tid];
    int rank = 0;
    for (int s = 0; s < n; ++s) rank += (gk[s] > k) ? 1 : 0;
    if (rank < NCAND) {
      int idx = 8191 - (int)(k & 0x1FFF);
      u32 o = (u32)(k >> 13);
      int f = idx / NUM_CLASSES, c = idx - f * NUM_CLASSES;
      float sc = float_of_ord(o);
      float off = (float)c * CLS_OFFSET;
      int g = img * F + f;
      candScore[rank] = sc; candFeat[rank] = f; candLabel[rank] = c;
      candBox[rank][0] = boxes[g * 4 + 0] + off;
      candBox[rank][1] = boxes[g * 4 + 1] + off;
      candBox[rank][2] = boxes[g * 4 + 2] + off;
      candBox[rank][3] = boxes[g * 4 + 3] + off;
    }
  }
  __syncthreads();

  // (e) pairwise IoU, folded triangular indexing: 19900 pairs (j < i)
  for (int p = tid; p < (NCAND * (NCAND - 1)) / 2; p += 1024) {
    int r = p / (NCAND / 2), cc = p - r * (NCAND / 2);
    int i, j;
    if (cc <= r) { i = r + 1; j = cc; }
    else         { i = NCAND - 1 - r; j = NCAND - 1 - cc; }
    float ax1 = candBox[i][0], ay1 = candBox[i][1], ax2 = candBox[i][2], ay2 = candBox[i][3];
    float bx1 = candBox[j][0], by1 = candBox[j][1], bx2 = candBox[j][2], by2 = candBox[j][3];
    float areaA = (ax2 - ax1) * (ay2 - ay1);
    float areaB = (bx2 - bx1) * (by2 - by1);
    float lx = fmaxf(ax1, bx1), ly = fmaxf(ay1, by1);
    float rx = fminf(ax2, bx2), ry = fminf(ay2, by2);
    float w = fmaxf(rx - lx, 0.0f), h = fmaxf(ry - ly, 0.0f);
    float inter = w * h;
    float iou = inter / ((areaA + areaB - inter) + 1e-9f);
    if (iou > NMS_THR) atomicOr(&supp[i][j >> 6], 1ull << (j & 63));
  }
  __syncthreads();

  // (f) serial greedy NMS, depth-4 software pipeline, keep-mask in registers
  if (tid == 0) {
    u64 ka = 0, kb = 0, kc = 0, kd = 0;
    int nf = 0;
    u64 A0, A1, A2, A3, B0, B1, B2, B3, C0, C1, C2, C3, D0, D1, D2, D3;
    float sA, sB, sC, sD;
#define LOADR(S0, S1, S2, S3, SS, ii) \
    { S0 = supp[ii][0]; S1 = supp[ii][1]; S2 = supp[ii][2]; S3 = supp[ii][3]; SS = candScore[ii]; }
#define PROCR(S0, S1, S2, S3, SS, ii) \
    { bool sup = ((S0 & ka) | (S1 & kb) | (S2 & kc) | (S3 & kd)) != 0ull;      \
      if ((SS > -0.5f) && !sup) {                                              \
        u64 bit = 1ull << ((ii) & 63);                                         \
        if ((ii) < 64) ka |= bit; else if ((ii) < 128) kb |= bit;              \
        else if ((ii) < 192) kc |= bit; else kd |= bit;                        \
        if (nf < MAX_SEGS) finIdx[nf] = (ii);                                  \
        ++nf; } }
    LOADR(A0, A1, A2, A3, sA, 0)
    LOADR(B0, B1, B2, B3, sB, 1)
    LOADR(C0, C1, C2, C3, sC, 2)
    LOADR(D0, D1, D2, D3, sD, 3)
    for (int i = 0; i < NCAND; i += 4) {
      PROCR(A0, A1, A2, A3, sA, i)
      if (i + 4 < NCAND) LOADR(A0, A1, A2, A3, sA, i + 4)
      PROCR(B0, B1, B2, B3, sB, i + 1)
      if (i + 5 < NCAND) LOADR(B0, B1, B2, B3, sB, i + 5)
      PROCR(C0, C1, C2, C3, sC, i + 2)
      if (i + 6 < NCAND) LOADR(C0, C1, C2, C3, sC, i + 6)
      PROCR(D0, D1, D2, D3, sD, i + 3)
      if (i + 7 < NCAND) LOADR(D0, D1, D2, D3, sD, i + 7)
    }
    int m = nf < MAX_SEGS ? nf : MAX_SEGS;
    finCnt = m;
    for (int i = 0; i < NCAND && m < MAX_SEGS; ++i) {
      u64 w = (i < 64) ? ka : (i < 128) ? kb : (i < 192) ? kc : kd;
      if (!((w >> (i & 63)) & 1ull)) finIdx[m++] = i;
    }
#undef LOADR
#undef PROCR
  }
  __syncthreads();

  if (tid < MAX_SEGS) {
    int keptN = finCnt;
    int i = finIdx[tid];
    bool v = tid < keptN;
    int o = img * MAX_SEGS + tid;
    out[o] = (float)candLabel[i];
    out[scoresOff + (size_t)o] = v ? candScore[i] : 0.0f;
    out[validOff + (size_t)o] = v ? 1.0f : 0.0f;
    finFeatWs[o] = candFeat[i];
    finValidWs[o] = v ? 1 : 0;
  }
}

// ---------------- K3: bilinear 128->512 upsample + threshold ----------------
__global__ void __launch_bounds__(256)
interp_kernel(const float* __restrict__ seg, const int* __restrict__ finFeat,
              const int* __restrict__ finValid, float* __restrict__ outMasks, int F) {
  int bm = blockIdx.x;
  int tid = threadIdx.x;
  int q = tid & 127;                        // col group -> cols 4q..4q+3
  int Q = blockIdx.y * 2 + (tid >> 7);      // src quad -> output rows 4Q..4Q+3
  float* obase = outMasks + (size_t)bm * (OH * OW) + (size_t)(4 * Q) * OW;

  if (!finValid[bm]) {
    v4f z = {0.0f, 0.0f, 0.0f, 0.0f};
#pragma unroll
    for (int r = 0; r < 4; ++r)
      __builtin_nontemporal_store(z, reinterpret_cast<v4f*>(obase + r * OW) + q);
    return;
  }
  int img = bm / MAX_SEGS;
  int f = finFeat[bm];
  const float* src = seg + ((size_t)(img * F + f)) * (FH * FW);

  int rm = (Q > 0) ? Q - 1 : 0;
  int rp = (Q < 127) ? Q + 1 : 127;
  const float* prm = src + (size_t)rm * FW;
  const float* pr0 = src + (size_t)Q * FW;
  const float* prp = src + (size_t)rp * FW;
  int qm = (q > 0) ? q - 1 : 0;
  int qp = (q < FW - 1) ? q + 1 : FW - 1;

  double am = prm[qm], a0 = pr0[qm], ap = prp[qm];
  double bmv = prm[q], b0 = pr0[q], bp = prp[q];
  double cm = prm[qp], c0 = pr0[qp], cp = prp[qp];

  double A[4], Bv[4], C[4];
  if (Q == 0) {
    A[0] = a0; Bv[0] = b0; C[0] = c0;
    A[1] = a0; Bv[1] = b0; C[1] = c0;
  } else {
    A[0] = 0.375 * am + 0.625 * a0;  Bv[0] = 0.375 * bmv + 0.625 * b0;  C[0] = 0.375 * cm + 0.625 * c0;
    A[1] = 0.125 * am + 0.875 * a0;  Bv[1] = 0.125 * bmv + 0.875 * b0;  C[1] = 0.125 * cm + 0.875 * c0;
  }
  if (Q == 127) {
    A[2] = a0; Bv[2] = b0; C[2] = c0;
    A[3] = a0; Bv[3] = b0; C[3] = c0;
  } else {
    A[2] = 0.875 * a0 + 0.125 * ap;  Bv[2] = 0.875 * b0 + 0.125 * bp;  C[2] = 0.875 * c0 + 0.125 * cp;
    A[3] = 0.625 * a0 + 0.375 * ap;  Bv[3] = 0.625 * b0 + 0.375 * bp;  C[3] = 0.625 * c0 + 0.375 * cp;
  }

#pragma unroll
  for (int r = 0; r < 4; ++r) {
    double px0 = (q == 0)      ? Bv[r] : (0.375 * A[r] + 0.625 * Bv[r]);
    double px1 = (q == 0)      ? Bv[r] : (0.125 * A[r] + 0.875 * Bv[r]);
    double px2 = (q == FW - 1) ? Bv[r] : (0.875 * Bv[r] + 0.125 * C[r]);
    double px3 = (q == FW - 1) ? Bv[r] : (0.625 * Bv[r] + 0.375 * C[r]);
    v4f res;
    res.x = (px0 > 0.0) ? 1.0f : 0.0f;
    res.y = (px1 > 0.0) ? 1.0f : 0.0f;
    res.z = (px2 > 0.0) ? 1.0f : 0.0f;
    res.w = (px3 > 0.0) ? 1.0f : 0.0f;
    __builtin_nontemporal_store(res, reinterpret_cast<v4f*>(obase + r * OW) + q);
  }
}

// ---------------- host launch ----------------
extern "C" void kernel_launch(void* const* d_in, const int* in_sizes, int n_in,
                              void* d_out, int out_size, void* d_ws, size_t ws_size,
                              hipStream_t stream) {
  const float* cls = (const float*)d_in[0];
  const float* seg = (const float*)d_in[1];
  const int B = 2;  // fixed by setup_inputs
  int totalF = in_sizes[0] / NCLS1;      // 200
  int F = totalF / B;                    // 100

  float* out = (float*)d_out;
  float* boxes   = (float*)d_ws;                       // totalF*4 floats
  int*   validF  = (int*)(boxes + (size_t)totalF * 4);
  int*   finFeat = validF + totalF;
  int*   finValid = finFeat + B * MAX_SEGS;

  const size_t labelsN   = (size_t)B * MAX_SEGS;             // 100
  const size_t maskElems = (size_t)B * MAX_SEGS * OH * OW;   // 26,214,400
  const size_t scoresOff = labelsN + maskElems;
  const size_t validOff  = scoresOff + labelsN;

  box_kernel<<<totalF, 256, 0, stream>>>(seg, boxes, validF);
  select_nms_kernel<<<B, 1024, 0, stream>>>(cls, boxes, validF, F, out,
                                            finFeat, finValid, scoresOff, validOff);
  interp_kernel<<<dim3(B * MAX_SEGS, OH / 8), 256, 0, stream>>>(seg, finFeat, finValid,
                                                                out + labelsN, F);
}